// Round 8
// baseline (363.612 us; speedup 1.0000x reference)
//
#include <hip/hip_runtime.h>
#include <math.h>

#define N_TOKENS 32768
#define N_EMBED  8192
#define EMB      32
#define DECAYF   0.99f
#define OMDF     0.01f

// ---- workspace layout (float-element offsets) ----
#define WS_WW    0                         // ||w||^2        [N_EMBED]
#define WS_ENC   (WS_WW + N_EMBED)         // indices (int)  [N_TOKENS]
#define WS_BINS  (WS_ENC + N_TOKENS)       // counts         [N_EMBED]
#define WS_ESUM  (WS_BINS + N_EMBED)       // scatter sum    [N_EMBED*EMB]
#define WS_LOSS  (WS_ESUM + N_EMBED*EMB)   // loss accum     [1]

// ---- output layout (float-element offsets), reference return order ----
#define OUT_ZQ   0
#define OUT_LOSS (N_TOKENS*EMB)            // 1048576
#define OUT_IDX  (OUT_LOSS + 1)            // 1048577
#define OUT_NW   (OUT_IDX + N_TOKENS)      // 1081345
#define OUT_CS   (OUT_NW + N_EMBED*EMB)    // 1343489

// ============ K0: ||w||^2 per codebook row ============
__global__ void k_ww(const float* __restrict__ w, float* __restrict__ ww) {
    int r = blockIdx.x * blockDim.x + threadIdx.x;
    if (r >= N_EMBED) return;
    const float4* wp = (const float4*)(w + (size_t)r * EMB);
    float acc = 0.f;
#pragma unroll
    for (int i = 0; i < 8; ++i) {
        float4 v = wp[i];
        acc += v.x * v.x + v.y * v.y + v.z * v.z + v.w * v.w;
    }
    ww[r] = acc;
}

// ============ K1: fused normalize + distance + argmin ============
// Block = 1024 threads = 16 waves; block owns 128 tokens (2 per lane, T=2).
// Wave wv scans codebook slice [wv*512, (wv+1)*512); weight/ww addresses are
// wave-uniform -> scalar path. Key = ww[n] - 2*dot (per-token constant zz
// dropped: ordering preserved).
//
// r5/r6 lesson: out-of-loop asm pins do NOT keep read-only values register-
// resident; LLVM remats/spills them (VGPR_Count 40/52, VALUBusy 63/67%).
// Fix: volatile pins INSIDE the loop body -> zr must be in VGPRs every
// iteration, so keeping them resident is the only sane allocation.
// waves_per_eu(4,4): grid = 256 blocks = 1 block/CU = 4 waves/EU -> the
// pinned occupancy is what the launch achieves anyway; budget = 128 VGPRs.
#define SLICES 16
#define ROWS_PER_SLICE (N_EMBED / SLICES)   // 512
#define TOK_PER_BLOCK  128

#define PIN8(a,b,c,d,e,f,g,h) \
    asm volatile("" : "+v"(a), "+v"(b), "+v"(c), "+v"(d), \
                      "+v"(e), "+v"(f), "+v"(g), "+v"(h))

__global__ __attribute__((amdgpu_flat_work_group_size(1024, 1024),
                          amdgpu_waves_per_eu(4, 4)))
void k_argmin(
        const float* __restrict__ z, const float* __restrict__ weight,
        const float* __restrict__ ww, int* __restrict__ enc,
        float* __restrict__ zn) {
    __shared__ float sBest[SLICES][2][64];
    __shared__ int   sIdx[SLICES][2][64];

    const int lane = threadIdx.x & 63;
    const int wv   = __builtin_amdgcn_readfirstlane(threadIdx.x >> 6);
    const int tok0 = blockIdx.x * TOK_PER_BLOCK + lane;        // token for t=0
    const int tok1 = tok0 + 64;                                // token for t=1

    // --- load + normalize both token rows (redundant per wave; ~1% of loop cost)
    float zr0[EMB], zr1[EMB];
    {
        const float4* zp0 = (const float4*)(z + (size_t)tok0 * EMB);
        const float4* zp1 = (const float4*)(z + (size_t)tok1 * EMB);
        float acc0 = 0.f, acc1 = 0.f;
#pragma unroll
        for (int i = 0; i < 8; ++i) {
            float4 v0 = zp0[i];
            float4 v1 = zp1[i];
            acc0 += v0.x * v0.x + v0.y * v0.y + v0.z * v0.z + v0.w * v0.w;
            acc1 += v1.x * v1.x + v1.y * v1.y + v1.z * v1.z + v1.w * v1.w;
            zr0[4*i+0] = v0.x; zr0[4*i+1] = v0.y; zr0[4*i+2] = v0.z; zr0[4*i+3] = v0.w;
            zr1[4*i+0] = v1.x; zr1[4*i+1] = v1.y; zr1[4*i+2] = v1.z; zr1[4*i+3] = v1.w;
        }
        float n0 = fmaxf(sqrtf(acc0), 1e-12f);
        float n1 = fmaxf(sqrtf(acc1), 1e-12f);
#pragma unroll
        for (int k = 0; k < EMB; ++k) { zr0[k] = zr0[k] / n0; zr1[k] = zr1[k] / n1; }
    }

    // wave 0 persists normalized z for k_token (out z_q region)
    if (wv == 0) {
        float4* o0 = (float4*)(zn + (size_t)tok0 * EMB);
        float4* o1 = (float4*)(zn + (size_t)tok1 * EMB);
#pragma unroll
        for (int i = 0; i < 8; ++i) {
            float4 a, b;
            a.x = zr0[4*i+0]; a.y = zr0[4*i+1]; a.z = zr0[4*i+2]; a.w = zr0[4*i+3];
            b.x = zr1[4*i+0]; b.y = zr1[4*i+1]; b.z = zr1[4*i+2]; b.w = zr1[4*i+3];
            o0[i] = a; o1[i] = b;
        }
    }

    const int n0r = wv * ROWS_PER_SLICE;
    const float* wrow  = weight + (size_t)n0r * EMB;
    const float* wwrow = ww + n0r;

    float best0 = 3.4e38f, best1 = 3.4e38f;
    int bidx0 = 0, bidx1 = 0;

#pragma unroll 2
    for (int i = 0; i < ROWS_PER_SLICE; ++i) {
        // In-loop residency pins: zero instructions, but every iteration
        // requires all 64 floats in VGPRs -> allocator keeps them resident.
        PIN8(zr0[0], zr0[1], zr0[2], zr0[3], zr0[4], zr0[5], zr0[6], zr0[7]);
        PIN8(zr0[8], zr0[9], zr0[10], zr0[11], zr0[12], zr0[13], zr0[14], zr0[15]);
        PIN8(zr0[16], zr0[17], zr0[18], zr0[19], zr0[20], zr0[21], zr0[22], zr0[23]);
        PIN8(zr0[24], zr0[25], zr0[26], zr0[27], zr0[28], zr0[29], zr0[30], zr0[31]);
        PIN8(zr1[0], zr1[1], zr1[2], zr1[3], zr1[4], zr1[5], zr1[6], zr1[7]);
        PIN8(zr1[8], zr1[9], zr1[10], zr1[11], zr1[12], zr1[13], zr1[14], zr1[15]);
        PIN8(zr1[16], zr1[17], zr1[18], zr1[19], zr1[20], zr1[21], zr1[22], zr1[23]);
        PIN8(zr1[24], zr1[25], zr1[26], zr1[27], zr1[28], zr1[29], zr1[30], zr1[31]);

        const float4* wp = (const float4*)(wrow + (size_t)i * EMB);
        float a00 = 0.f, a01 = 0.f, a10 = 0.f, a11 = 0.f;   // 2 chains per token
#pragma unroll
        for (int k = 0; k < 8; ++k) {
            float4 w4 = wp[k];
            a00 = fmaf(zr0[4*k+0], w4.x, a00);
            a01 = fmaf(zr0[4*k+1], w4.y, a01);
            a10 = fmaf(zr1[4*k+0], w4.x, a10);
            a11 = fmaf(zr1[4*k+1], w4.y, a11);
            a00 = fmaf(zr0[4*k+2], w4.z, a00);
            a01 = fmaf(zr0[4*k+3], w4.w, a01);
            a10 = fmaf(zr1[4*k+2], w4.z, a10);
            a11 = fmaf(zr1[4*k+3], w4.w, a11);
        }
        float wwv = wwrow[i];
        float key0 = fmaf(-2.f, a00 + a01, wwv);
        float key1 = fmaf(-2.f, a10 + a11, wwv);
        bool c0 = key0 < best0;            // strict < keeps FIRST min (jnp.argmin)
        bool c1 = key1 < best1;
        best0 = c0 ? key0 : best0;  bidx0 = c0 ? (n0r + i) : bidx0;
        best1 = c1 ? key1 : best1;  bidx1 = c1 ? (n0r + i) : bidx1;
    }

    sBest[wv][0][lane] = best0;  sIdx[wv][0][lane] = bidx0;
    sBest[wv][1][lane] = best1;  sIdx[wv][1][lane] = bidx1;
    __syncthreads();

    if (threadIdx.x < 2 * 64) {
        const int l = threadIdx.x & 63;
        const int t = threadIdx.x >> 6;
        float b = sBest[0][t][l];
        int   bi = sIdx[0][t][l];
#pragma unroll
        for (int s = 1; s < SLICES; ++s) {
            float ob = sBest[s][t][l];
            int   oi = sIdx[s][t][l];
            bool c = ob < b;               // ascending slices: ties keep lower index
            b  = c ? ob : b;
            bi = c ? oi : bi;
        }
        enc[blockIdx.x * TOK_PER_BLOCK + t * 64 + l] = bi;
    }
}

// ============ K3: per-token outputs + scatters + loss ============
// Reads zn from out[OUT_ZQ] and overwrites it in place with z_q_st (each
// address is read before written, within the same thread).
__global__ void k_token(const float* __restrict__ weight,
                        const int* __restrict__ enc, float* __restrict__ out,
                        float* __restrict__ bins, float* __restrict__ esum,
                        float* __restrict__ loss) {
    int t = blockIdx.x * blockDim.x + threadIdx.x;
    int idx = enc[t];
    float4* zq = (float4*)(out + OUT_ZQ + (size_t)t * EMB);
    const float4* wp = (const float4*)(weight + (size_t)idx * EMB);

    float lacc = 0.f;
#pragma unroll
    for (int i = 0; i < 8; ++i) {
        float4 zv = zq[i];                 // normalized z (staged by k_argmin)
        float4 wv = wp[i];
        float4 d, o;
        d.x = wv.x - zv.x; d.y = wv.y - zv.y; d.z = wv.z - zv.z; d.w = wv.w - zv.w;
        lacc += d.x * d.x + d.y * d.y + d.z * d.z + d.w * d.w;
        // straight-through: z + (z_q - z), replicating reference fp rounding
        o.x = zv.x + d.x; o.y = zv.y + d.y; o.z = zv.z + d.z; o.w = zv.w + d.w;
        zq[i] = o;
        atomicAdd(esum + (size_t)idx * EMB + 4 * i + 0, zv.x);
        atomicAdd(esum + (size_t)idx * EMB + 4 * i + 1, zv.y);
        atomicAdd(esum + (size_t)idx * EMB + 4 * i + 2, zv.z);
        atomicAdd(esum + (size_t)idx * EMB + 4 * i + 3, zv.w);
    }
    out[OUT_IDX + t] = (float)idx;
    atomicAdd(bins + idx, 1.0f);

    // wave-level loss reduction, one atomic per wave
#pragma unroll
    for (int off = 32; off > 0; off >>= 1) lacc += __shfl_xor(lacc, off, 64);
    if ((threadIdx.x & 63) == 0) atomicAdd(loss, lacc);
}

// ============ K4: EMA codebook update + finalize loss ============
__global__ void k_ema(const float* __restrict__ weight, const float* __restrict__ cs,
                      const float* __restrict__ bins, const float* __restrict__ esum,
                      const float* __restrict__ loss, float* __restrict__ out) {
    int n = blockIdx.x * blockDim.x + threadIdx.x;
    if (n == 0) {
        out[OUT_LOSS] = loss[0] * (1.0f / (float)(N_TOKENS * EMB));  // BETA = 1
    }
    if (n >= N_EMBED) return;

    float b = bins[n];
    out[OUT_CS + n] = cs[n] * DECAYF + b * OMDF;

    bool zero = (b == 0.0f);
    float safe = zero ? 1.0f : b;

    float w[EMB], en[EMB];
    const float* wrow = weight + (size_t)n * EMB;
    const float* erow = esum + (size_t)n * EMB;
    float nacc = 0.f;
#pragma unroll
    for (int i = 0; i < EMB; ++i) {
        w[i] = wrow[i];
        en[i] = erow[i] / safe;
        nacc += en[i] * en[i];
    }
    float nn = fmaxf(sqrtf(nacc), 1e-12f);
#pragma unroll
    for (int i = 0; i < EMB; ++i) {
        en[i] = zero ? w[i] : (en[i] / nn);
    }
    float acc2 = 0.f;
    float nw[EMB];
#pragma unroll
    for (int i = 0; i < EMB; ++i) {
        nw[i] = w[i] * DECAYF + en[i] * OMDF;
        acc2 += nw[i] * nw[i];
    }
    float n2 = fmaxf(sqrtf(acc2), 1e-12f);
#pragma unroll
    for (int i = 0; i < EMB; ++i) {
        out[OUT_NW + (size_t)n * EMB + i] = nw[i] / n2;
    }
}

// ============ launcher ============
extern "C" void kernel_launch(void* const* d_in, const int* in_sizes, int n_in,
                              void* d_out, int out_size, void* d_ws, size_t ws_size,
                              hipStream_t stream) {
    const float* z  = (const float*)d_in[0];
    const float* w  = (const float*)d_in[1];
    const float* cs = (const float*)d_in[2];
    float* out = (float*)d_out;
    float* ws  = (float*)d_ws;

    float* zn   = out + OUT_ZQ;          // staged normalized z (overwritten by k_token)
    float* ww   = ws + WS_WW;
    int*   enc  = (int*)(ws + WS_ENC);
    float* bins = ws + WS_BINS;
    float* esum = ws + WS_ESUM;
    float* loss = ws + WS_LOSS;

    // zero the accumulators (bins, esum, loss are contiguous)
    hipMemsetAsync(bins, 0, (size_t)(N_EMBED + N_EMBED * EMB + 1) * sizeof(float), stream);

    k_ww<<<N_EMBED / 256, 256, 0, stream>>>(w, ww);
    k_argmin<<<N_TOKENS / TOK_PER_BLOCK, 1024, 0, stream>>>(z, w, ww, enc, zn);
    k_token<<<N_TOKENS / 256, 256, 0, stream>>>(w, enc, out, bins, esum, loss);
    k_ema<<<(N_EMBED + 255) / 256, 256, 0, stream>>>(w, cs, bins, esum, loss, out);
}